// Round 16
// baseline (103.229 us; speedup 1.0000x reference)
//
#include <hip/hip_runtime.h>
#include <math.h>

#define HH 480
#define WW 640
#define HW (HH*WW)

#define NB1 1200   // K1 blocks
#define NB3 3600   // K3 blocks (20 x 60 x 3)

__device__ __forceinline__ unsigned bf16rne(float f) {
    unsigned u = __float_as_uint(f);
    return (u + 0x7fffu + ((u >> 16) & 1u)) >> 16;
}

// ---------------- K1: resample + photo + CE + masks (partials, no atomics) ----------------

__device__ __forceinline__ float sample1(const float* __restrict__ row, float x) {
    float x0 = floorf(x);
    float w1 = x - x0;
    int xi = (int)x0;
    float v0 = (xi >= 0 && xi < WW) ? row[xi] : 0.f;
    float v1 = (xi + 1 >= 0 && xi + 1 < WW) ? row[xi + 1] : 0.f;
    return v0 * (1.f - w1) + v1 * w1;
}

__global__ __launch_bounds__(256) void k_resample(
    const float* __restrict__ left, const float* __restrict__ right,
    const float* __restrict__ dispL, const float* __restrict__ dispR,
    float* __restrict__ rir, float* __restrict__ ril,
    unsigned char* __restrict__ maskb, float* __restrict__ part1)
{
    __shared__ float red[4][6];
    int tid = threadIdx.x;
    int idx = blockIdx.x * blockDim.x + tid;
    int h = idx / WW;
    int w = idx - h * WW;
    float dL = dispL[idx];
    float dR = dispR[idx];
    float xl = (float)w - dL;   // sample right view at j - dispL
    float xr = (float)w + dR;   // sample left view  at j + dispR
    float photoL = 0.f, photoR = 0.f;
    #pragma unroll
    for (int c = 0; c < 3; ++c) {
        float rv = sample1(right + c*HW + h*WW, xl);
        float lv = sample1(left  + c*HW + h*WW, xr);
        rir[c*HW + idx] = rv;
        ril[c*HW + idx] = lv;
        photoL += fabsf(left [c*HW + idx] - rv);
        photoR += fabsf(right[c*HW + idx] - lv);
    }
    float rdr = sample1(dispR + h*WW, xl);
    float rdl = sample1(dispL + h*WW, xr);
    float pl = __expf(-0.6931f * fabsf(dL - rdr));
    float pr = __expf(-0.6931f * fabsf(dR - rdl));
    float mL = (pl > 0.5f) ? 1.f : 0.f;
    float mR = (pr > 0.5f) ? 1.f : 0.f;
    maskb[idx] = (unsigned char)((mL > 0.f ? 1u : 0u) | (mR > 0.f ? 2u : 0u));

    float vals[6];
    vals[0] = 0.5f * photoL * mL;
    vals[1] = mL;
    vals[2] = 0.5f * photoR * mR;
    vals[3] = mR;
    vals[4] = log1pf(__expf(1.f - 2.f * pl));
    vals[5] = log1pf(__expf(1.f - 2.f * pr));

    int lane = tid & 63, wave = tid >> 6;
    #pragma unroll
    for (int k = 0; k < 6; ++k) {
        float v = vals[k];
        #pragma unroll
        for (int off = 32; off > 0; off >>= 1) v += __shfl_down(v, off);
        if (lane == 0) red[wave][k] = v;
    }
    __syncthreads();
    if (tid < 6)
        part1[blockIdx.x * 8 + tid] =
            red[0][tid] + red[1][tid] + red[2][tid] + red[3][tid];
}

// ---------------- K2: 9x9 LCN (separable), one (side,channel) per blockIdx.z ----------------
// block (32,8), region 32x8, halo 4: raw 16x40 per plane; grid (20,60,6) = 7200 blocks.
// z: side = z & 1, ch = z >> 1. side 0: A=left[ch], B=rir[ch] -> epem, cl16.
//                               side 1: A=right[ch], B=ril[ch] -> cr16.

__global__ __launch_bounds__(256) void k_lcnpack(
    const float* __restrict__ left, const float* __restrict__ right,
    const float* __restrict__ rir, const float* __restrict__ ril,
    unsigned* __restrict__ epem,
    unsigned short* __restrict__ cl16, unsigned short* __restrict__ cr16)
{
    __shared__ float raw[2][16][40];    // 5120 B
    __shared__ float2 hsp[2][16][32];   // 8192 B  (.x = sum, .y = sumsq)
    int tx = threadIdx.x, ty = threadIdx.y;
    int tid = ty * 32 + tx;
    int gx0 = blockIdx.x * 32, gy0 = blockIdx.y * 8;
    int side = blockIdx.z & 1, ch = blockIdx.z >> 1;
    const float* __restrict__ A = (side ? right : left) + ch*HW;   // real (std source)
    const float* __restrict__ B = (side ? ril   : rir) + ch*HW;    // reconstruction

    // stage: 2 planes x 16 x 40 = 1280 elems (plane = 640 elems!)
    for (int e = tid; e < 2*16*40; e += 256) {
        int a   = e / 640;           // FIX: plane size is 640, not 512
        int rem = e - a * 640;
        int r   = rem / 40;
        int x   = rem - r * 40;
        int gy = gy0 + r - 4, gx = gx0 + x - 4;
        float v = 0.f;
        if ((unsigned)gy < (unsigned)HH && (unsigned)gx < (unsigned)WW)
            v = (a ? B : A)[gy*WW + gx];
        ((float*)raw)[e] = v;
    }
    __syncthreads();

    // hpass: 2*16*8 = 256 groups of 4 outputs = 1 per thread
    {
        int f   = tid;
        int a   = f >> 7;
        int rem = f & 127;
        int r   = rem >> 3;
        int x0  = (rem & 7) * 4;
        const float* row = &raw[a][r][x0];
        float4 p0 = *(const float4*)(row);
        float4 p1 = *(const float4*)(row + 4);
        float4 p2 = *(const float4*)(row + 8);
        float v[12] = {p0.x, p0.y, p0.z, p0.w, p1.x, p1.y, p1.z, p1.w,
                       p2.x, p2.y, p2.z, p2.w};
        float sq[12];
        #pragma unroll
        for (int i = 0; i < 12; ++i) sq[i] = v[i] * v[i];
        float s0 = v[0]+v[1]+v[2]+v[3]+v[4]+v[5]+v[6]+v[7]+v[8];
        float q0 = sq[0]+sq[1]+sq[2]+sq[3]+sq[4]+sq[5]+sq[6]+sq[7]+sq[8];
        float s1 = s0 - v[0] + v[9];
        float q1 = q0 - sq[0] + sq[9];
        float s2 = s1 - v[1] + v[10];
        float q2 = q1 - sq[1] + sq[10];
        float s3 = s2 - v[2] + v[11];
        float q3 = q2 - sq[2] + sq[11];
        float4* out = (float4*)&hsp[a][r][x0];
        out[0] = make_float4(s0, q0, s1, q1);
        out[1] = make_float4(s2, q2, s3, q3);
    }
    __syncthreads();

    int idx = ch*HW + (gy0 + ty) * WW + gx0 + tx;
    float SA = 0.f, SA2 = 0.f, SB = 0.f, SB2 = 0.f;
    #pragma unroll
    for (int dy = 0; dy < 9; ++dy) {
        float2 ha = hsp[0][ty + dy][tx];
        float2 hb = hsp[1][ty + dy][tx];
        SA  += ha.x;
        SA2 += ha.y;
        SB  += hb.x;
        SB2 += hb.y;
    }
    float meanA = SA * (1.f/81.f);
    float stdA  = sqrtf(fmaxf(SA2 * (1.f/81.f) - meanA * meanA, 0.f)) * (81.f/80.f);
    float lcnA  = (raw[0][ty + 4][tx + 4] - meanA) / (stdA + 1e-5f);
    float meanB = SB * (1.f/81.f);
    float stdB  = sqrtf(fmaxf(SB2 * (1.f/81.f) - meanB * meanB, 0.f)) * (81.f/80.f);
    float lcnB  = (raw[1][ty + 4][tx + 4] - meanB) / (stdB + 1e-5f);
    float cost  = fabsf((lcnA - lcnB) * stdA);
    if (side == 0) {
        float g = raw[0][ty + 4][tx + 4];
        epem[idx] = bf16rne(__expf(0.5f * g)) | (bf16rne(__expf(-0.5f * g)) << 16);
        cl16[idx] = (unsigned short)bf16rne(cost);
    } else {
        cr16[idx] = (unsigned short)bf16rne(cost);
    }
}

// ---------------- K3: 12x12 ASW + reduction (2-wave row-split) ----------------
// block (32,2,2) = 128 threads = 2 waves (wz = threadIdx.z); channel c = blockIdx.z.
// Thread (tx,ty,*): 4 outputs (gx0+tx, gy0+4ty+i), i=0..3; region 32x8/block.
// Tap rows kap 0..14 split: wave 0 -> 0..7, wave 1 -> 8..14; partials merged via LDS.
// Tile uint2: .x = bf16(Ep)|bf16(Em)<<16; .y = bf16(cL)|bf16(cR)<<16.
// OOB halo: g=0 => Ep=Em=1.0, costs 0. Per tap: t = min(Em_c*Ep_q, Ep_c*Em_q).

#define T3H 19
#define T3W 43

__global__ __launch_bounds__(128) void k_asw_reduce(
    const unsigned* __restrict__ epem,
    const unsigned short* __restrict__ cl16, const unsigned short* __restrict__ cr16,
    const unsigned char* __restrict__ maskb,
    float* __restrict__ part3)
{
    __shared__ uint2 tile[T3H][T3W];      // 6536 B
    __shared__ float part[2][4][3][32];   // 3072 B (wave-1 partials: [ty][i][k][tx])
    int tx = threadIdx.x, ty = threadIdx.y, wz = threadIdx.z;
    int tid = tx + 32 * ty + 64 * wz;
    int c = blockIdx.z;
    int gx0 = blockIdx.x * 32, gy0 = blockIdx.y * 8;

    for (int e = tid; e < T3H * T3W; e += 128) {
        int r   = e / T3W;
        int x   = e - r * T3W;
        int gy = gy0 + r - 6, gx = gx0 + x - 6;
        uint2 v = make_uint2(0x3f803f80u, 0u);   // g=0: Ep=Em=1, costs 0
        if ((unsigned)gy < (unsigned)HH && (unsigned)gx < (unsigned)WW) {
            int o = c*HW + gy*WW + gx;
            v.x = epem[o];
            v.y = (unsigned)cl16[o] | ((unsigned)cr16[o] << 16);
        }
        tile[r][x] = v;
    }
    __syncthreads();

    int ty4 = 4 * ty;
    float epc[4], emc[4];
    #pragma unroll
    for (int i = 0; i < 4; ++i) {
        unsigned vc = tile[ty4 + i + 6][tx + 6].x;
        epc[i] = __uint_as_float(vc << 16);
        emc[i] = __uint_as_float(vc & 0xffff0000u);
    }

    float wg[4] = {0.f,0.f,0.f,0.f}, aL[4] = {0.f,0.f,0.f,0.f}, aR[4] = {0.f,0.f,0.f,0.f};

    auto taprow = [&](int kap, int i0, int i1) {
        const uint2* row = &tile[ty4 + kap][tx];
        #pragma unroll
        for (int dx = 0; dx < 12; ++dx) {
            uint2 v = row[dx];
            float ep  = __uint_as_float(v.x << 16);
            float em  = __uint_as_float(v.x & 0xffff0000u);
            float clv = __uint_as_float(v.y << 16);
            float crv = __uint_as_float(v.y & 0xffff0000u);
            #pragma unroll
            for (int i = 0; i < 4; ++i) {
                if (i >= i0 && i <= i1) {
                    float t = fminf(emc[i] * ep, epc[i] * em);
                    wg[i] += t;
                    aL[i] = fmaf(t, clv, aL[i]);
                    aR[i] = fmaf(t, crv, aR[i]);
                }
            }
        }
    };

    if (wz == 0) {
        taprow(0, 0, 0);
        taprow(1, 0, 1);
        taprow(2, 0, 2);
        taprow(3, 0, 3);
        taprow(4, 0, 3);
        taprow(5, 0, 3);
        taprow(6, 0, 3);
        taprow(7, 0, 3);
    } else {
        taprow(8, 0, 3);
        taprow(9, 0, 3);
        taprow(10, 0, 3);
        taprow(11, 0, 3);
        taprow(12, 1, 3);
        taprow(13, 2, 3);
        taprow(14, 3, 3);
        #pragma unroll
        for (int i = 0; i < 4; ++i) {
            part[ty][i][0][tx] = wg[i];
            part[ty][i][1][tx] = aL[i];
            part[ty][i][2][tx] = aR[i];
        }
    }
    __syncthreads();

    if (wz == 0) {
        float v0 = 0.f, v2 = 0.f;
        #pragma unroll
        for (int i = 0; i < 4; ++i) {
            float w  = wg[i] + part[ty][i][0][tx];
            float l  = aL[i] + part[ty][i][1][tx];
            float r  = aR[i] + part[ty][i][2][tx];
            int idx = (gy0 + ty4 + i) * WW + gx0 + tx;
            unsigned m = maskb[idx];
            if (m & 1u) v0 += 0.5f * (l / w);
            if (m & 2u) v2 += 0.5f * (r / w);
        }
        #pragma unroll
        for (int off = 32; off > 0; off >>= 1) {
            v0 += __shfl_down(v0, off);
            v2 += __shfl_down(v2, off);
        }
        if (tid == 0) {
            int bid = (blockIdx.z * gridDim.y + blockIdx.y) * gridDim.x + blockIdx.x;
            part3[bid * 8 + 0] = v0;
            part3[bid * 8 + 1] = v2;
        }
    }
}

// ---------------- K4: reduce partials + finalize ----------------

__global__ __launch_bounds__(256) void k_final(
    const float* __restrict__ part1, const float* __restrict__ part3,
    const float* __restrict__ weight, float* __restrict__ out)
{
    __shared__ float red[4][6];
    int tid = threadIdx.x;
    float v[6] = {0.f, 0.f, 0.f, 0.f, 0.f, 0.f};
    for (int b = tid; b < NB1; b += 256) {
        #pragma unroll
        for (int k = 0; k < 6; ++k) v[k] += part1[b * 8 + k];
    }
    for (int b = tid; b < NB3; b += 256) {
        v[0] += part3[b * 8 + 0];
        v[2] += part3[b * 8 + 1];
    }
    int lane = tid & 63, wave = tid >> 6;
    #pragma unroll
    for (int k = 0; k < 6; ++k) {
        float s = v[k];
        #pragma unroll
        for (int off = 32; off > 0; off >>= 1) s += __shfl_down(s, off);
        if (lane == 0) red[wave][k] = s;
    }
    __syncthreads();
    if (tid == 0) {
        float a[6];
        #pragma unroll
        for (int k = 0; k < 6; ++k)
            a[k] = red[0][k] + red[1][k] + red[2][k] + red[3][k];
        float loss_valid = a[0] / (3.f * a[1] + 1e-6f) + a[2] / (3.f * a[3] + 1e-6f);
        float loss_invalid = (a[4] + a[5]) * (1.f / (float)HW);
        out[0] = weight[0] * (0.9f * loss_valid + 0.1f * loss_invalid);
    }
}

// ---------------- launch ----------------

extern "C" void kernel_launch(void* const* d_in, const int* in_sizes, int n_in,
                              void* d_out, int out_size, void* d_ws, size_t ws_size,
                              hipStream_t stream)
{
    const float* left  = (const float*)d_in[0];
    const float* right = (const float*)d_in[1];
    const float* dispL = (const float*)d_in[2];
    const float* dispR = (const float*)d_in[3];
    // d_in[4] = dispmap_gt (unused), d_in[5] = brk (unused)
    const float* weight = (const float*)d_in[6];

    float* ws    = (float*)d_ws;
    float* rir   = ws;                                  // 3*HW f32
    float* ril   = rir + 3*HW;                          // 3*HW f32
    unsigned* epem = (unsigned*)(ws + 6*HW);            // 3*HW u32
    unsigned short* cl16 = (unsigned short*)(ws + 9*HW);            // 3*HW u16
    unsigned short* cr16 = (unsigned short*)(ws + 9*HW) + 3*HW;     // 3*HW u16
    unsigned char* maskb = (unsigned char*)(ws + 12*HW);            // HW bytes
    float* part1 = ws + 12*HW + HW/4;                   // NB1*8
    float* part3 = part1 + NB1*8;                       // NB3*8

    k_resample<<<NB1, 256, 0, stream>>>(left, right, dispL, dispR, rir, ril, maskb, part1);

    dim3 blk2(32, 8);
    dim3 grd2(WW / 32, HH / 8, 6);
    k_lcnpack<<<grd2, blk2, 0, stream>>>(left, right, rir, ril, epem, cl16, cr16);

    dim3 blk3(32, 2, 2);
    dim3 grd3(WW / 32, HH / 8, 3);
    k_asw_reduce<<<grd3, blk3, 0, stream>>>(epem, cl16, cr16, maskb, part3);

    k_final<<<1, 256, 0, stream>>>(part1, part3, weight, (float*)d_out);
}

// Round 17
// 75.829 us; speedup vs baseline: 1.3613x; 1.3613x over previous
//
#include <hip/hip_runtime.h>
#include <math.h>

#define HH 480
#define WW 640
#define HW (HH*WW)

#define NB1 1200   // K1 blocks
#define NB3 3600   // K3 blocks (20 x 60 x 3)

__device__ __forceinline__ unsigned bf16rne(float f) {
    unsigned u = __float_as_uint(f);
    return (u + 0x7fffu + ((u >> 16) & 1u)) >> 16;
}

// ---------------- K1: resample + photo + CE + masks (partials, no atomics) ----------------

__device__ __forceinline__ float sample1(const float* __restrict__ row, float x) {
    float x0 = floorf(x);
    float w1 = x - x0;
    int xi = (int)x0;
    float v0 = (xi >= 0 && xi < WW) ? row[xi] : 0.f;
    float v1 = (xi + 1 >= 0 && xi + 1 < WW) ? row[xi + 1] : 0.f;
    return v0 * (1.f - w1) + v1 * w1;
}

__global__ __launch_bounds__(256) void k_resample(
    const float* __restrict__ left, const float* __restrict__ right,
    const float* __restrict__ dispL, const float* __restrict__ dispR,
    float* __restrict__ rir, float* __restrict__ ril,
    unsigned char* __restrict__ maskb, float* __restrict__ part1)
{
    __shared__ float red[4][6];
    int tid = threadIdx.x;
    int idx = blockIdx.x * blockDim.x + tid;
    int h = idx / WW;
    int w = idx - h * WW;
    float dL = dispL[idx];
    float dR = dispR[idx];
    float xl = (float)w - dL;   // sample right view at j - dispL
    float xr = (float)w + dR;   // sample left view  at j + dispR
    float photoL = 0.f, photoR = 0.f;
    #pragma unroll
    for (int c = 0; c < 3; ++c) {
        float rv = sample1(right + c*HW + h*WW, xl);
        float lv = sample1(left  + c*HW + h*WW, xr);
        rir[c*HW + idx] = rv;
        ril[c*HW + idx] = lv;
        photoL += fabsf(left [c*HW + idx] - rv);
        photoR += fabsf(right[c*HW + idx] - lv);
    }
    float rdr = sample1(dispR + h*WW, xl);
    float rdl = sample1(dispL + h*WW, xr);
    float pl = __expf(-0.6931f * fabsf(dL - rdr));
    float pr = __expf(-0.6931f * fabsf(dR - rdl));
    float mL = (pl > 0.5f) ? 1.f : 0.f;
    float mR = (pr > 0.5f) ? 1.f : 0.f;
    maskb[idx] = (unsigned char)((mL > 0.f ? 1u : 0u) | (mR > 0.f ? 2u : 0u));

    float vals[6];
    vals[0] = 0.5f * photoL * mL;
    vals[1] = mL;
    vals[2] = 0.5f * photoR * mR;
    vals[3] = mR;
    vals[4] = log1pf(__expf(1.f - 2.f * pl));
    vals[5] = log1pf(__expf(1.f - 2.f * pr));

    int lane = tid & 63, wave = tid >> 6;
    #pragma unroll
    for (int k = 0; k < 6; ++k) {
        float v = vals[k];
        #pragma unroll
        for (int off = 32; off > 0; off >>= 1) v += __shfl_down(v, off);
        if (lane == 0) red[wave][k] = v;
    }
    __syncthreads();
    if (tid < 6)
        part1[blockIdx.x * 8 + tid] =
            red[0][tid] + red[1][tid] + red[2][tid] + red[3][tid];
}

// ---------------- K2: 9x9 LCN (separable), one (side,channel) per blockIdx.z ----------------
// block (32,8), region 32x8, halo 4: raw 16x40 per plane; grid (20,60,6) = 7200 blocks.
// z: side = z & 1, ch = z >> 1. side 0: A=left[ch], B=rir[ch] -> epem, cl16.
//                               side 1: A=right[ch], B=ril[ch] -> cr16.

__global__ __launch_bounds__(256) void k_lcnpack(
    const float* __restrict__ left, const float* __restrict__ right,
    const float* __restrict__ rir, const float* __restrict__ ril,
    unsigned* __restrict__ epem,
    unsigned short* __restrict__ cl16, unsigned short* __restrict__ cr16)
{
    __shared__ float raw[2][16][40];    // 5120 B
    __shared__ float2 hsp[2][16][32];   // 8192 B  (.x = sum, .y = sumsq)
    int tx = threadIdx.x, ty = threadIdx.y;
    int tid = ty * 32 + tx;
    int gx0 = blockIdx.x * 32, gy0 = blockIdx.y * 8;
    int side = blockIdx.z & 1, ch = blockIdx.z >> 1;
    const float* __restrict__ A = (side ? right : left) + ch*HW;   // real (std source)
    const float* __restrict__ B = (side ? ril   : rir) + ch*HW;    // reconstruction

    // stage: 2 planes x 16 x 40 = 1280 elems (plane = 640 elems)
    for (int e = tid; e < 2*16*40; e += 256) {
        int a   = e / 640;           // plane size is 640 (FIXED from e>>9)
        int rem = e - a * 640;
        int r   = rem / 40;
        int x   = rem - r * 40;
        int gy = gy0 + r - 4, gx = gx0 + x - 4;
        float v = 0.f;
        if ((unsigned)gy < (unsigned)HH && (unsigned)gx < (unsigned)WW)
            v = (a ? B : A)[gy*WW + gx];
        ((float*)raw)[e] = v;
    }
    __syncthreads();

    // hpass: 2*16*8 = 256 groups of 4 outputs = 1 per thread
    {
        int f   = tid;
        int a   = f >> 7;
        int rem = f & 127;
        int r   = rem >> 3;
        int x0  = (rem & 7) * 4;
        const float* row = &raw[a][r][x0];
        float4 p0 = *(const float4*)(row);
        float4 p1 = *(const float4*)(row + 4);
        float4 p2 = *(const float4*)(row + 8);
        float v[12] = {p0.x, p0.y, p0.z, p0.w, p1.x, p1.y, p1.z, p1.w,
                       p2.x, p2.y, p2.z, p2.w};
        float sq[12];
        #pragma unroll
        for (int i = 0; i < 12; ++i) sq[i] = v[i] * v[i];
        float s0 = v[0]+v[1]+v[2]+v[3]+v[4]+v[5]+v[6]+v[7]+v[8];
        float q0 = sq[0]+sq[1]+sq[2]+sq[3]+sq[4]+sq[5]+sq[6]+sq[7]+sq[8];
        float s1 = s0 - v[0] + v[9];
        float q1 = q0 - sq[0] + sq[9];
        float s2 = s1 - v[1] + v[10];
        float q2 = q1 - sq[1] + sq[10];
        float s3 = s2 - v[2] + v[11];
        float q3 = q2 - sq[2] + sq[11];
        float4* out = (float4*)&hsp[a][r][x0];
        out[0] = make_float4(s0, q0, s1, q1);
        out[1] = make_float4(s2, q2, s3, q3);
    }
    __syncthreads();

    int idx = ch*HW + (gy0 + ty) * WW + gx0 + tx;
    float SA = 0.f, SA2 = 0.f, SB = 0.f, SB2 = 0.f;
    #pragma unroll
    for (int dy = 0; dy < 9; ++dy) {
        float2 ha = hsp[0][ty + dy][tx];
        float2 hb = hsp[1][ty + dy][tx];
        SA  += ha.x;
        SA2 += ha.y;
        SB  += hb.x;
        SB2 += hb.y;
    }
    float meanA = SA * (1.f/81.f);
    float stdA  = sqrtf(fmaxf(SA2 * (1.f/81.f) - meanA * meanA, 0.f)) * (81.f/80.f);
    float lcnA  = (raw[0][ty + 4][tx + 4] - meanA) / (stdA + 1e-5f);
    float meanB = SB * (1.f/81.f);
    float stdB  = sqrtf(fmaxf(SB2 * (1.f/81.f) - meanB * meanB, 0.f)) * (81.f/80.f);
    float lcnB  = (raw[1][ty + 4][tx + 4] - meanB) / (stdB + 1e-5f);
    float cost  = fabsf((lcnA - lcnB) * stdA);
    if (side == 0) {
        float g = raw[0][ty + 4][tx + 4];
        epem[idx] = bf16rne(__expf(0.5f * g)) | (bf16rne(__expf(-0.5f * g)) << 16);
        cl16[idx] = (unsigned short)bf16rne(cost);
    } else {
        cr16[idx] = (unsigned short)bf16rne(cost);
    }
}

// ---------------- K3: 12x12 ASW + reduction (1-wave blocks, unpacked f32 tile) ----------------
// block (32,2) = 64 threads = 1 wave; channel c = blockIdx.z; thread (tx,ty):
// 4 outputs (gx0+tx, gy0+4ty+i), i=0..3; region 32x8/block; grid (20,60,3)=3600.
// Tile float4 = (Ep, Em, cL, cR), all f32 (pre-expanded from bf16 at staging).
// OOB halo: g=0 => Ep=Em=1.0, costs 0 (matches zero-pad reference).
// Per tap: t = exp(-|g_c-g_q|/2) = min(Em_c*Ep_q, Ep_c*Em_q) — no unpack in the loop.

#define T3H 19
#define T3W 43

__global__ __launch_bounds__(64) void k_asw_reduce(
    const unsigned* __restrict__ epem,
    const unsigned short* __restrict__ cl16, const unsigned short* __restrict__ cr16,
    const unsigned char* __restrict__ maskb,
    float* __restrict__ part3)
{
    __shared__ float4 tile[T3H][T3W];   // 13072 B
    int tx = threadIdx.x, ty = threadIdx.y;
    int tid = tx + 32 * ty;
    int c = blockIdx.z;
    int gx0 = blockIdx.x * 32, gy0 = blockIdx.y * 8;

    for (int e = tid; e < T3H * T3W; e += 64) {
        int r   = e / T3W;
        int x   = e - r * T3W;
        int gy = gy0 + r - 6, gx = gx0 + x - 6;
        float4 v = make_float4(1.f, 1.f, 0.f, 0.f);   // g=0: Ep=Em=1, costs 0
        if ((unsigned)gy < (unsigned)HH && (unsigned)gx < (unsigned)WW) {
            int o = c*HW + gy*WW + gx;
            unsigned pe = epem[o];
            v.x = __uint_as_float(pe << 16);
            v.y = __uint_as_float(pe & 0xffff0000u);
            v.z = __uint_as_float((unsigned)cl16[o] << 16);
            v.w = __uint_as_float((unsigned)cr16[o] << 16);
        }
        tile[r][x] = v;
    }
    __syncthreads();

    int ty4 = 4 * ty;
    float epc[4], emc[4];
    #pragma unroll
    for (int i = 0; i < 4; ++i) {
        float4 cv = tile[ty4 + i + 6][tx + 6];
        epc[i] = cv.x;
        emc[i] = cv.y;
    }

    float wg[4] = {0.f,0.f,0.f,0.f}, aL[4] = {0.f,0.f,0.f,0.f}, aR[4] = {0.f,0.f,0.f,0.f};

    auto taprow = [&](int kap, int i0, int i1) {
        const float4* row = &tile[ty4 + kap][tx];
        #pragma unroll
        for (int dx = 0; dx < 12; ++dx) {
            float4 v = row[dx];
            #pragma unroll
            for (int i = 0; i < 4; ++i) {
                if (i >= i0 && i <= i1) {
                    float t = fminf(emc[i] * v.x, epc[i] * v.y);
                    wg[i] += t;
                    aL[i] = fmaf(t, v.z, aL[i]);
                    aR[i] = fmaf(t, v.w, aR[i]);
                }
            }
        }
    };

    taprow(0, 0, 0);
    taprow(1, 0, 1);
    taprow(2, 0, 2);
    for (int kap = 3; kap <= 11; ++kap)   // rolled bulk: all 4 outputs eligible
        taprow(kap, 0, 3);
    taprow(12, 1, 3);
    taprow(13, 2, 3);
    taprow(14, 3, 3);

    float v0 = 0.f, v2 = 0.f;
    #pragma unroll
    for (int i = 0; i < 4; ++i) {
        int idx = (gy0 + ty4 + i) * WW + gx0 + tx;
        unsigned m = maskb[idx];
        float aswL = aL[i] / wg[i];
        float aswR = aR[i] / wg[i];
        if (m & 1u) v0 += 0.5f * aswL;
        if (m & 2u) v2 += 0.5f * aswR;
    }

    #pragma unroll
    for (int off = 32; off > 0; off >>= 1) {
        v0 += __shfl_down(v0, off);
        v2 += __shfl_down(v2, off);
    }
    if (tid == 0) {
        int bid = (blockIdx.z * gridDim.y + blockIdx.y) * gridDim.x + blockIdx.x;
        part3[bid * 8 + 0] = v0;
        part3[bid * 8 + 1] = v2;
    }
}

// ---------------- K4: reduce partials + finalize ----------------

__global__ __launch_bounds__(256) void k_final(
    const float* __restrict__ part1, const float* __restrict__ part3,
    const float* __restrict__ weight, float* __restrict__ out)
{
    __shared__ float red[4][6];
    int tid = threadIdx.x;
    float v[6] = {0.f, 0.f, 0.f, 0.f, 0.f, 0.f};
    for (int b = tid; b < NB1; b += 256) {
        #pragma unroll
        for (int k = 0; k < 6; ++k) v[k] += part1[b * 8 + k];
    }
    for (int b = tid; b < NB3; b += 256) {
        v[0] += part3[b * 8 + 0];
        v[2] += part3[b * 8 + 1];
    }
    int lane = tid & 63, wave = tid >> 6;
    #pragma unroll
    for (int k = 0; k < 6; ++k) {
        float s = v[k];
        #pragma unroll
        for (int off = 32; off > 0; off >>= 1) s += __shfl_down(s, off);
        if (lane == 0) red[wave][k] = s;
    }
    __syncthreads();
    if (tid == 0) {
        float a[6];
        #pragma unroll
        for (int k = 0; k < 6; ++k)
            a[k] = red[0][k] + red[1][k] + red[2][k] + red[3][k];
        float loss_valid = a[0] / (3.f * a[1] + 1e-6f) + a[2] / (3.f * a[3] + 1e-6f);
        float loss_invalid = (a[4] + a[5]) * (1.f / (float)HW);
        out[0] = weight[0] * (0.9f * loss_valid + 0.1f * loss_invalid);
    }
}

// ---------------- launch ----------------

extern "C" void kernel_launch(void* const* d_in, const int* in_sizes, int n_in,
                              void* d_out, int out_size, void* d_ws, size_t ws_size,
                              hipStream_t stream)
{
    const float* left  = (const float*)d_in[0];
    const float* right = (const float*)d_in[1];
    const float* dispL = (const float*)d_in[2];
    const float* dispR = (const float*)d_in[3];
    // d_in[4] = dispmap_gt (unused), d_in[5] = brk (unused)
    const float* weight = (const float*)d_in[6];

    float* ws    = (float*)d_ws;
    float* rir   = ws;                                  // 3*HW f32
    float* ril   = rir + 3*HW;                          // 3*HW f32
    unsigned* epem = (unsigned*)(ws + 6*HW);            // 3*HW u32
    unsigned short* cl16 = (unsigned short*)(ws + 9*HW);            // 3*HW u16
    unsigned short* cr16 = (unsigned short*)(ws + 9*HW) + 3*HW;     // 3*HW u16
    unsigned char* maskb = (unsigned char*)(ws + 12*HW);            // HW bytes
    float* part1 = ws + 12*HW + HW/4;                   // NB1*8
    float* part3 = part1 + NB1*8;                       // NB3*8

    k_resample<<<NB1, 256, 0, stream>>>(left, right, dispL, dispR, rir, ril, maskb, part1);

    dim3 blk2(32, 8);
    dim3 grd2(WW / 32, HH / 8, 6);
    k_lcnpack<<<grd2, blk2, 0, stream>>>(left, right, rir, ril, epem, cl16, cr16);

    dim3 blk3(32, 2);
    dim3 grd3(WW / 32, HH / 8, 3);
    k_asw_reduce<<<grd3, blk3, 0, stream>>>(epem, cl16, cr16, maskb, part3);

    k_final<<<1, 256, 0, stream>>>(part1, part3, weight, (float*)d_out);
}

// Round 18
// 71.574 us; speedup vs baseline: 1.4423x; 1.0594x over previous
//
#include <hip/hip_runtime.h>
#include <math.h>

#define HH 480
#define WW 640
#define HW (HH*WW)

#define NB1 1200   // K1 blocks
#define NB3 3600   // K3 blocks (20 x 60 x 3)

typedef float v2f __attribute__((ext_vector_type(2)));

__device__ __forceinline__ unsigned bf16rne(float f) {
    unsigned u = __float_as_uint(f);
    return (u + 0x7fffu + ((u >> 16) & 1u)) >> 16;
}

// ---------------- K1: resample + photo + CE + masks (partials, no atomics) ----------------

__device__ __forceinline__ float sample1(const float* __restrict__ row, float x) {
    float x0 = floorf(x);
    float w1 = x - x0;
    int xi = (int)x0;
    float v0 = (xi >= 0 && xi < WW) ? row[xi] : 0.f;
    float v1 = (xi + 1 >= 0 && xi + 1 < WW) ? row[xi + 1] : 0.f;
    return v0 * (1.f - w1) + v1 * w1;
}

__global__ __launch_bounds__(256) void k_resample(
    const float* __restrict__ left, const float* __restrict__ right,
    const float* __restrict__ dispL, const float* __restrict__ dispR,
    float* __restrict__ rir, float* __restrict__ ril,
    unsigned char* __restrict__ maskb, float* __restrict__ part1)
{
    __shared__ float red[4][6];
    int tid = threadIdx.x;
    int idx = blockIdx.x * blockDim.x + tid;
    int h = idx / WW;
    int w = idx - h * WW;
    float dL = dispL[idx];
    float dR = dispR[idx];
    float xl = (float)w - dL;   // sample right view at j - dispL
    float xr = (float)w + dR;   // sample left view  at j + dispR
    float photoL = 0.f, photoR = 0.f;
    #pragma unroll
    for (int c = 0; c < 3; ++c) {
        float rv = sample1(right + c*HW + h*WW, xl);
        float lv = sample1(left  + c*HW + h*WW, xr);
        rir[c*HW + idx] = rv;
        ril[c*HW + idx] = lv;
        photoL += fabsf(left [c*HW + idx] - rv);
        photoR += fabsf(right[c*HW + idx] - lv);
    }
    float rdr = sample1(dispR + h*WW, xl);
    float rdl = sample1(dispL + h*WW, xr);
    float pl = __expf(-0.6931f * fabsf(dL - rdr));
    float pr = __expf(-0.6931f * fabsf(dR - rdl));
    float mL = (pl > 0.5f) ? 1.f : 0.f;
    float mR = (pr > 0.5f) ? 1.f : 0.f;
    maskb[idx] = (unsigned char)((mL > 0.f ? 1u : 0u) | (mR > 0.f ? 2u : 0u));

    float vals[6];
    vals[0] = 0.5f * photoL * mL;
    vals[1] = mL;
    vals[2] = 0.5f * photoR * mR;
    vals[3] = mR;
    vals[4] = log1pf(__expf(1.f - 2.f * pl));
    vals[5] = log1pf(__expf(1.f - 2.f * pr));

    int lane = tid & 63, wave = tid >> 6;
    #pragma unroll
    for (int k = 0; k < 6; ++k) {
        float v = vals[k];
        #pragma unroll
        for (int off = 32; off > 0; off >>= 1) v += __shfl_down(v, off);
        if (lane == 0) red[wave][k] = v;
    }
    __syncthreads();
    if (tid < 6)
        part1[blockIdx.x * 8 + tid] =
            red[0][tid] + red[1][tid] + red[2][tid] + red[3][tid];
}

// ---------------- K2: 9x9 LCN (separable), one (side,channel) per blockIdx.z ----------------
// block (32,8), region 32x8, halo 4: raw 16x40 per plane; grid (20,60,6) = 7200 blocks.
// z: side = z & 1, ch = z >> 1. side 0: A=left[ch], B=rir[ch] -> epem, cl16.
//                               side 1: A=right[ch], B=ril[ch] -> cr16.

__global__ __launch_bounds__(256) void k_lcnpack(
    const float* __restrict__ left, const float* __restrict__ right,
    const float* __restrict__ rir, const float* __restrict__ ril,
    unsigned* __restrict__ epem,
    unsigned short* __restrict__ cl16, unsigned short* __restrict__ cr16)
{
    __shared__ float raw[2][16][40];    // 5120 B
    __shared__ float2 hsp[2][16][32];   // 8192 B  (.x = sum, .y = sumsq)
    int tx = threadIdx.x, ty = threadIdx.y;
    int tid = ty * 32 + tx;
    int gx0 = blockIdx.x * 32, gy0 = blockIdx.y * 8;
    int side = blockIdx.z & 1, ch = blockIdx.z >> 1;
    const float* __restrict__ A = (side ? right : left) + ch*HW;   // real (std source)
    const float* __restrict__ B = (side ? ril   : rir) + ch*HW;    // reconstruction

    for (int e = tid; e < 2*16*40; e += 256) {
        int a   = e / 640;
        int rem = e - a * 640;
        int r   = rem / 40;
        int x   = rem - r * 40;
        int gy = gy0 + r - 4, gx = gx0 + x - 4;
        float v = 0.f;
        if ((unsigned)gy < (unsigned)HH && (unsigned)gx < (unsigned)WW)
            v = (a ? B : A)[gy*WW + gx];
        ((float*)raw)[e] = v;
    }
    __syncthreads();

    // hpass: 2*16*8 = 256 groups of 4 outputs = 1 per thread
    {
        int f   = tid;
        int a   = f >> 7;
        int rem = f & 127;
        int r   = rem >> 3;
        int x0  = (rem & 7) * 4;
        const float* row = &raw[a][r][x0];
        float4 p0 = *(const float4*)(row);
        float4 p1 = *(const float4*)(row + 4);
        float4 p2 = *(const float4*)(row + 8);
        float v[12] = {p0.x, p0.y, p0.z, p0.w, p1.x, p1.y, p1.z, p1.w,
                       p2.x, p2.y, p2.z, p2.w};
        float sq[12];
        #pragma unroll
        for (int i = 0; i < 12; ++i) sq[i] = v[i] * v[i];
        float s0 = v[0]+v[1]+v[2]+v[3]+v[4]+v[5]+v[6]+v[7]+v[8];
        float q0 = sq[0]+sq[1]+sq[2]+sq[3]+sq[4]+sq[5]+sq[6]+sq[7]+sq[8];
        float s1 = s0 - v[0] + v[9];
        float q1 = q0 - sq[0] + sq[9];
        float s2 = s1 - v[1] + v[10];
        float q2 = q1 - sq[1] + sq[10];
        float s3 = s2 - v[2] + v[11];
        float q3 = q2 - sq[2] + sq[11];
        float4* out = (float4*)&hsp[a][r][x0];
        out[0] = make_float4(s0, q0, s1, q1);
        out[1] = make_float4(s2, q2, s3, q3);
    }
    __syncthreads();

    int idx = ch*HW + (gy0 + ty) * WW + gx0 + tx;
    float SA = 0.f, SA2 = 0.f, SB = 0.f, SB2 = 0.f;
    #pragma unroll
    for (int dy = 0; dy < 9; ++dy) {
        float2 ha = hsp[0][ty + dy][tx];
        float2 hb = hsp[1][ty + dy][tx];
        SA  += ha.x;
        SA2 += ha.y;
        SB  += hb.x;
        SB2 += hb.y;
    }
    float meanA = SA * (1.f/81.f);
    float stdA  = sqrtf(fmaxf(SA2 * (1.f/81.f) - meanA * meanA, 0.f)) * (81.f/80.f);
    float lcnA  = (raw[0][ty + 4][tx + 4] - meanA) / (stdA + 1e-5f);
    float meanB = SB * (1.f/81.f);
    float stdB  = sqrtf(fmaxf(SB2 * (1.f/81.f) - meanB * meanB, 0.f)) * (81.f/80.f);
    float lcnB  = (raw[1][ty + 4][tx + 4] - meanB) / (stdB + 1e-5f);
    float cost  = fabsf((lcnA - lcnB) * stdA);
    if (side == 0) {
        float g = raw[0][ty + 4][tx + 4];
        epem[idx] = bf16rne(__expf(0.5f * g)) | (bf16rne(__expf(-0.5f * g)) << 16);
        cl16[idx] = (unsigned short)bf16rne(cost);
    } else {
        cr16[idx] = (unsigned short)bf16rne(cost);
    }
}

// ---------------- K3: 12x12 ASW + reduction (1-wave blocks, packed-f32 pairs) ----------------
// block (32,2) = 64 threads = 1 wave; channel c = blockIdx.z; thread (tx,ty):
// 4 outputs (gx0+tx, gy0+4ty+i), i=0..3, packed as v2f pairs (0,1)/(2,3).
// region 32x8/block; grid (20,60,3)=3600. Tile float4 = (Ep, Em, cL, cR) f32.
// OOB halo: g=0 => Ep=Em=1, costs 0. Per tap: t = min(Em_c*Ep_q, Ep_c*Em_q).
// Bulk rows (all 4 outputs eligible) use v_pk_{mul,add,fma}_f32 via v2f;
// edge rows stay scalar into the vector halves (same accumulation order).

#define T3H 19
#define T3W 43

__global__ __launch_bounds__(64) void k_asw_reduce(
    const unsigned* __restrict__ epem,
    const unsigned short* __restrict__ cl16, const unsigned short* __restrict__ cr16,
    const unsigned char* __restrict__ maskb,
    float* __restrict__ part3)
{
    __shared__ float4 tile[T3H][T3W];   // 13072 B
    int tx = threadIdx.x, ty = threadIdx.y;
    int tid = tx + 32 * ty;
    int c = blockIdx.z;
    int gx0 = blockIdx.x * 32, gy0 = blockIdx.y * 8;

    for (int e = tid; e < T3H * T3W; e += 64) {
        int r   = e / T3W;
        int x   = e - r * T3W;
        int gy = gy0 + r - 6, gx = gx0 + x - 6;
        float4 v = make_float4(1.f, 1.f, 0.f, 0.f);   // g=0: Ep=Em=1, costs 0
        if ((unsigned)gy < (unsigned)HH && (unsigned)gx < (unsigned)WW) {
            int o = c*HW + gy*WW + gx;
            unsigned pe = epem[o];
            v.x = __uint_as_float(pe << 16);
            v.y = __uint_as_float(pe & 0xffff0000u);
            v.z = __uint_as_float((unsigned)cl16[o] << 16);
            v.w = __uint_as_float((unsigned)cr16[o] << 16);
        }
        tile[r][x] = v;
    }
    __syncthreads();

    int ty4 = 4 * ty;
    float4 c0 = tile[ty4 + 6][tx + 6];
    float4 c1 = tile[ty4 + 7][tx + 6];
    float4 c2 = tile[ty4 + 8][tx + 6];
    float4 c3 = tile[ty4 + 9][tx + 6];
    v2f epc01 = {c0.x, c1.x}, emc01 = {c0.y, c1.y};
    v2f epc23 = {c2.x, c3.x}, emc23 = {c2.y, c3.y};

    v2f wg01 = {0.f,0.f}, wg23 = {0.f,0.f};
    v2f aL01 = {0.f,0.f}, aL23 = {0.f,0.f};
    v2f aR01 = {0.f,0.f}, aR23 = {0.f,0.f};

    // scalar tap for one output half: h=0 -> .x, h=1 -> .y of the pair regs
    auto tap1 = [&](float ep_, float em_, float cl_, float cr_,
                    v2f& wg, v2f& aL, v2f& aR, float epc_, float emc_, int h) {
        float t = fminf(emc_ * ep_, epc_ * em_);
        if (h == 0) { wg.x += t; aL.x = fmaf(t, cl_, aL.x); aR.x = fmaf(t, cr_, aR.x); }
        else        { wg.y += t; aL.y = fmaf(t, cl_, aL.y); aR.y = fmaf(t, cr_, aR.y); }
    };

    auto taprow_edge = [&](int kap, int i0, int i1) {
        const float4* row = &tile[ty4 + kap][tx];
        #pragma unroll
        for (int dx = 0; dx < 12; ++dx) {
            float4 v = row[dx];
            if (i0 <= 0 && 0 <= i1) tap1(v.x, v.y, v.z, v.w, wg01, aL01, aR01, epc01.x, emc01.x, 0);
            if (i0 <= 1 && 1 <= i1) tap1(v.x, v.y, v.z, v.w, wg01, aL01, aR01, epc01.y, emc01.y, 1);
            if (i0 <= 2 && 2 <= i1) tap1(v.x, v.y, v.z, v.w, wg23, aL23, aR23, epc23.x, emc23.x, 0);
            if (i0 <= 3 && 3 <= i1) tap1(v.x, v.y, v.z, v.w, wg23, aL23, aR23, epc23.y, emc23.y, 1);
        }
    };

    auto taprow_pk = [&](int kap) {
        const float4* row = &tile[ty4 + kap][tx];
        #pragma unroll
        for (int dx = 0; dx < 12; ++dx) {
            float4 v = row[dx];
            v2f ep = {v.x, v.x}, em = {v.y, v.y};
            v2f cl = {v.z, v.z}, cr = {v.w, v.w};
            v2f t01 = __builtin_elementwise_min(emc01 * ep, epc01 * em);
            v2f t23 = __builtin_elementwise_min(emc23 * ep, epc23 * em);
            wg01 += t01;
            wg23 += t23;
            aL01 = __builtin_elementwise_fma(t01, cl, aL01);
            aL23 = __builtin_elementwise_fma(t23, cl, aL23);
            aR01 = __builtin_elementwise_fma(t01, cr, aR01);
            aR23 = __builtin_elementwise_fma(t23, cr, aR23);
        }
    };

    taprow_edge(0, 0, 0);
    taprow_edge(1, 0, 1);
    taprow_edge(2, 0, 2);
    for (int kap = 3; kap <= 11; ++kap)   // all 4 outputs eligible
        taprow_pk(kap);
    taprow_edge(12, 1, 3);
    taprow_edge(13, 2, 3);
    taprow_edge(14, 3, 3);

    float wgf[4] = {wg01.x, wg01.y, wg23.x, wg23.y};
    float aLf[4] = {aL01.x, aL01.y, aL23.x, aL23.y};
    float aRf[4] = {aR01.x, aR01.y, aR23.x, aR23.y};

    float v0 = 0.f, v2 = 0.f;
    #pragma unroll
    for (int i = 0; i < 4; ++i) {
        int idx = (gy0 + ty4 + i) * WW + gx0 + tx;
        unsigned m = maskb[idx];
        float aswL = aLf[i] / wgf[i];
        float aswR = aRf[i] / wgf[i];
        if (m & 1u) v0 += 0.5f * aswL;
        if (m & 2u) v2 += 0.5f * aswR;
    }

    #pragma unroll
    for (int off = 32; off > 0; off >>= 1) {
        v0 += __shfl_down(v0, off);
        v2 += __shfl_down(v2, off);
    }
    if (tid == 0) {
        int bid = (blockIdx.z * gridDim.y + blockIdx.y) * gridDim.x + blockIdx.x;
        part3[bid * 8 + 0] = v0;
        part3[bid * 8 + 1] = v2;
    }
}

// ---------------- K4: reduce partials + finalize ----------------

__global__ __launch_bounds__(256) void k_final(
    const float* __restrict__ part1, const float* __restrict__ part3,
    const float* __restrict__ weight, float* __restrict__ out)
{
    __shared__ float red[4][6];
    int tid = threadIdx.x;
    float v[6] = {0.f, 0.f, 0.f, 0.f, 0.f, 0.f};
    for (int b = tid; b < NB1; b += 256) {
        #pragma unroll
        for (int k = 0; k < 6; ++k) v[k] += part1[b * 8 + k];
    }
    for (int b = tid; b < NB3; b += 256) {
        v[0] += part3[b * 8 + 0];
        v[2] += part3[b * 8 + 1];
    }
    int lane = tid & 63, wave = tid >> 6;
    #pragma unroll
    for (int k = 0; k < 6; ++k) {
        float s = v[k];
        #pragma unroll
        for (int off = 32; off > 0; off >>= 1) s += __shfl_down(s, off);
        if (lane == 0) red[wave][k] = s;
    }
    __syncthreads();
    if (tid == 0) {
        float a[6];
        #pragma unroll
        for (int k = 0; k < 6; ++k)
            a[k] = red[0][k] + red[1][k] + red[2][k] + red[3][k];
        float loss_valid = a[0] / (3.f * a[1] + 1e-6f) + a[2] / (3.f * a[3] + 1e-6f);
        float loss_invalid = (a[4] + a[5]) * (1.f / (float)HW);
        out[0] = weight[0] * (0.9f * loss_valid + 0.1f * loss_invalid);
    }
}

// ---------------- launch ----------------

extern "C" void kernel_launch(void* const* d_in, const int* in_sizes, int n_in,
                              void* d_out, int out_size, void* d_ws, size_t ws_size,
                              hipStream_t stream)
{
    const float* left  = (const float*)d_in[0];
    const float* right = (const float*)d_in[1];
    const float* dispL = (const float*)d_in[2];
    const float* dispR = (const float*)d_in[3];
    // d_in[4] = dispmap_gt (unused), d_in[5] = brk (unused)
    const float* weight = (const float*)d_in[6];

    float* ws    = (float*)d_ws;
    float* rir   = ws;                                  // 3*HW f32
    float* ril   = rir + 3*HW;                          // 3*HW f32
    unsigned* epem = (unsigned*)(ws + 6*HW);            // 3*HW u32
    unsigned short* cl16 = (unsigned short*)(ws + 9*HW);            // 3*HW u16
    unsigned short* cr16 = (unsigned short*)(ws + 9*HW) + 3*HW;     // 3*HW u16
    unsigned char* maskb = (unsigned char*)(ws + 12*HW);            // HW bytes
    float* part1 = ws + 12*HW + HW/4;                   // NB1*8
    float* part3 = part1 + NB1*8;                       // NB3*8

    k_resample<<<NB1, 256, 0, stream>>>(left, right, dispL, dispR, rir, ril, maskb, part1);

    dim3 blk2(32, 8);
    dim3 grd2(WW / 32, HH / 8, 6);
    k_lcnpack<<<grd2, blk2, 0, stream>>>(left, right, rir, ril, epem, cl16, cr16);

    dim3 blk3(32, 2);
    dim3 grd3(WW / 32, HH / 8, 3);
    k_asw_reduce<<<grd3, blk3, 0, stream>>>(epem, cl16, cr16, maskb, part3);

    k_final<<<1, 256, 0, stream>>>(part1, part3, weight, (float*)d_out);
}